// Round 10
// baseline (435.635 us; speedup 1.0000x reference)
//
#include <hip/hip_runtime.h>
#include <hip/hip_fp16.h>

typedef _Float16 f16x8 __attribute__((ext_vector_type(8)));
typedef float f32x4 __attribute__((ext_vector_type(4)));

union U4H8 { uint4 u; f16x8 h; };
__device__ inline f16x8 asH(uint4 u){ U4H8 x; x.u = u; return x.h; }
__device__ inline unsigned int pk(float a, float b){
    __half2 h = __floats2half2_rn(a, b);
    union { __half2 h; unsigned int u; } c; c.h = h; return c.u;
}
// pack two floats to f16 with relu
__device__ inline unsigned int pkr(float a, float b){
    return pk(fmaxf(a, 0.f), fmaxf(b, 0.f));
}
__device__ inline unsigned short h16(float a){
    union { __half h; unsigned short s; } c; c.h = __float2half(a); return c.s;
}

// ws dword layout: frags uint4[28][64] = dwords [0,7168);
// b1f f32[16][64] @7168 | b2f f32[4][64] @8192 | b3f f32[8][64] @8448 |
// b4f f32[4][64] @8960 ; end 9216 dwords (36 KiB).
#define NFRAG 28
#define WS_B1 7168
#define WS_B2 8192
#define WS_B3 8448
#define WS_B4 8960

// frag fi: 0-1 conv1 (k=kh*8+kw, rows=oc); 2-14 conv2 (k=tap*16+ic, rows=oc);
//          15-26 fc1 (nt*6+kk, k=pos*12+oc2, rows=fc-col); 27 fc2 (rows=logit)
__global__ __launch_bounds__(256) void build_tables(
    const float* __restrict__ H1w, const float* __restrict__ H1b,
    const float* __restrict__ H2w, const float* __restrict__ H2b,
    const float* __restrict__ H3w, const float* __restrict__ H3b,
    const float* __restrict__ outw, const float* __restrict__ outb,
    unsigned int* __restrict__ ws)
{
    const int t = threadIdx.x, b = blockIdx.x;
    float* wsf = (float*)ws;

    if (b < NFRAG) {
        if (t < 64) {
            const int lane = t, ch = lane >> 4, oc = lane & 15;
            const int fi = b;
            unsigned short us[8];
            for (int j = 0; j < 8; ++j) {
                float w = 0.f;
                if (fi < 2) {                         // conv1
                    int kh = fi * 4 + ch;
                    if (kh < 5 && j < 5 && oc < 12) w = H1w[oc * 25 + kh * 5 + j];
                } else if (fi < 15) {                 // conv2 channels-last
                    int kk = fi - 2;
                    int tap = kk * 2 + (ch >> 1);
                    int ic = (ch & 1) * 8 + j;
                    if (tap < 25 && oc < 12) {
                        int kh = tap / 5, kw = tap % 5;
                        int q = oc >> 2, icl = -1;
                        if (q == 0)      { if (ic < 8) icl = ic; }
                        else if (q == 1) { if (ic >= 4 && ic < 12) icl = ic - 4; }
                        else             { if (ic < 4) icl = ic;
                                           else if (ic >= 8 && ic < 12) icl = ic - 4; }
                        if (icl >= 0) w = H2w[((oc * 8 + icl) * 5 + kh) * 5 + kw];
                    }
                } else if (fi < 27) {                 // fc1 (k = pos*12+oc2)
                    int idx = fi - 15, nt = idx / 6, kk = idx % 6;
                    int k = kk * 32 + ch * 8 + j;     // 0..191
                    int pos = k / 12, oc2 = k % 12;
                    int col = nt * 16 + oc;
                    if (col < 30) w = H3w[(oc2 * 16 + pos) * 30 + col];
                } else {                              // fc2
                    int k = ch * 8 + j;
                    if (k < 30 && oc < 10) w = outw[k * 10 + oc];
                }
                us[j] = h16(w);
            }
            uint4 u;
            u.x = us[0] | ((unsigned int)us[1] << 16);
            u.y = us[2] | ((unsigned int)us[3] << 16);
            u.z = us[4] | ((unsigned int)us[5] << 16);
            u.w = us[6] | ((unsigned int)us[7] << 16);
            ((uint4*)ws)[fi * 64 + lane] = u;
        }
    } else if (b == NFRAG) {        // b1f: entry e=tt*4+r, lane(ch,m); oc=4ch+r
        for (int idx = t; idx < 1024; idx += 256) {
            int e = idx >> 6, l2 = idx & 63;
            int tt = e >> 2, r = e & 3;
            int oc = 4 * (l2 >> 4) + r, m2 = l2 & 15;
            int oh = 2 * tt + (m2 >> 3), ow = m2 & 7;
            float v = 0.f;
            if (oc < 12) {
                v = H1b[oc * 64 + oh * 8 + ow];
                for (int kh = 0; kh < 5; ++kh)
                    for (int kw = 0; kw < 5; ++kw) {
                        int rr = 2 * oh + kh, cc = 2 * ow + kw;
                        if (rr < 2 || rr >= 18 || cc < 2 || cc >= 18)
                            v -= H1w[oc * 25 + kh * 5 + kw];
                    }
            }
            wsf[WS_B1 + e * 64 + l2] = v;
        }
    } else {                        // b2f + b3f + b4f
        {
            int e = t >> 6, l2 = t & 63;
            int oc = 4 * (l2 >> 4) + e, m2 = l2 & 15;
            int oh = m2 >> 2, ow = m2 & 3;
            float v = 0.f;
            if (oc < 12) {
                v = H2b[oc * 16 + oh * 4 + ow];
                for (int icl = 0; icl < 8; ++icl)
                    for (int kh = 0; kh < 5; ++kh)
                        for (int kw = 0; kw < 5; ++kw) {
                            int rr = 2 * oh + kh - 2, cc = 2 * ow + kw - 2;
                            if (rr < 0 || rr >= 8 || cc < 0 || cc >= 8)
                                v -= H2w[((oc * 8 + icl) * 5 + kh) * 5 + kw];
                        }
            }
            wsf[WS_B2 + e * 64 + l2] = v;
        }
        for (int i = t; i < 512; i += 256) {    // b3f: e = nt*4+r
            int e = i >> 6, l2 = i & 63;
            int nt = e >> 2, r = e & 3, ch = l2 >> 4;
            int j = nt * 16 + 4 * ch + r;
            wsf[WS_B3 + e * 64 + l2] = (j < 30) ? H3b[j] : 0.f;
        }
        {                                        // b4f: e = r
            int e = t >> 6, l2 = t & 63, ch = l2 >> 4;
            int j = 4 * ch + e;
            wsf[WS_B4 + e * 64 + l2] = (j < 10) ? outb[j] : 0.f;
        }
    }
}

// ---------------- main kernel ----------------
// Block LDS (22016 B):
//   per-wave region @ wave*4608 : ONE sample's h1c [144 pos][16 ch] half,
//     XOR-swizzled; processed twice (sample pass s=0,1). xs overlay @ bytes
//     0..960 of the region (dead after conv1 reads).
//   NOTE: the pad ring must be re-zeroed EVERY pass after the conv1 epilogue —
//   the x-interior write covers bytes 100..852, which contains several
//   swizzled ring entries (R9 bug: pass-1 ring held x data -> absmax 2.3).
//   shared h2 @ 18432 : 8 slots x 384 B, XOR-swizzled by slot
//   shared h3 @ 21504 : 8 slots x 64 B
#define H2B 18432
#define H3B 21504
__global__ __launch_bounds__(256, 7) void modernnet_mfma(
    const float* __restrict__ x, const unsigned int* __restrict__ ws,
    float* __restrict__ out)
{
    __shared__ uint4 lds4[1376];
    char* L = (char*)lds4;
    const int t = threadIdx.x, wave = t >> 6, l = t & 63;
    const int ch = l >> 4, m = l & 15;
    char* base = L + wave * 4608;
    const int sblk = blockIdx.x * 8;
    const int s0 = sblk + wave * 2;

    const uint4* fr = (const uint4*)ws;
    const float* wsf = (const float*)ws;

    // prefetch global x for both samples (hide HBM latency under frag loads)
    float4 xv0 = *(const float4*)(x + (size_t)(s0 + 0) * 256 + l * 4);
    float4 xv1 = *(const float4*)(x + (size_t)(s0 + 1) * 256 + l * 4);

    // conv1 weight + bias frags
    uint4 c1b0 = fr[0 * 64 + l], c1b1 = fr[1 * 64 + l];
    f32x4 b1f[4];
    #pragma unroll
    for (int tt = 0; tt < 4; ++tt)
        #pragma unroll
        for (int r = 0; r < 4; ++r) b1f[tt][r] = wsf[WS_B1 + (tt * 4 + r) * 64 + l];

    // conv2 per-lane read offsets — compile-time tap table, no divides
    int c2off[13];
    {
        const int mb = 24 * (m >> 2) + 2 * (m & 3);
        const int hb = (ch & 1) << 4;
        const int sel = (ch >> 1) & 1;
        #pragma unroll
        for (int kk = 0; kk < 13; ++kk) {
            const int t0 = 2 * kk;
            const int t1 = (2 * kk + 1 <= 24) ? 2 * kk + 1 : 24;
            const int p0 = (t0 / 5) * 12 + (t0 % 5);
            const int p1 = (t1 / 5) * 12 + (t1 % 5);
            int pos = mb + (sel ? p1 : p0);
            c2off[kk] = ((pos << 5) + hb) ^ ((pos & 12) << 2);
        }
    }

    // conv2 weights + bias (held across both passes)
    uint4 c2b[13];
    #pragma unroll
    for (int kk = 0; kk < 13; ++kk) c2b[kk] = fr[(2 + kk) * 64 + l];
    f32x4 b2f;
    #pragma unroll
    for (int r = 0; r < 4; ++r) b2f[r] = wsf[WS_B2 + r * 64 + l];

    // -------- two sample passes through the same 4608-B region --------
    #pragma unroll
    for (int s = 0; s < 2; ++s) {
        // zero xs overlay (bytes 0..960): rows 0-19 x 24 cols, f16 zeros
        {
            uint4 z; z.x = z.y = z.z = z.w = 0u;
            if (l < 60) ((uint4*)base)[l] = z;
        }
        // write x interior (16x16) -> f16, rows 2-17 cols 2-17
        {
            const float4 v = (s == 0) ? xv0 : xv1;
            const int r = l >> 2, c = (l & 3) * 4;
            char* dst = base + (r + 2) * 48 + (c + 2) * 2;
            ((unsigned int*)dst)[0] = pk(v.x, v.y);
            ((unsigned int*)dst)[1] = pk(v.z, v.w);
        }

        // conv1: 5 b128 reads. rd[i] (i<4) = rows 4i+2h+ch (h=m>>3);
        // tile tt: kh0-3 operand = rd[tt], kh4 operand = rd[tt+1] (only ch=0
        // lanes carry nonzero c1b1 weights; their rows = 4tt+2h+4 = correct).
        // rd[4] read wave-uniform row 16+2h (ch>0 rows would be OOB junk).
        uint4 rd[5];
        #pragma unroll
        for (int i = 0; i < 5; ++i) {
            const int cho = (i < 4) ? ch * 48 : 0;
            const unsigned int* p = (const unsigned int*)
                (base + (2 * i + (m >> 3)) * 96 + (m & 7) * 4 + cho);
            rd[i] = make_uint4(p[0], p[1], p[2], p[3]);
        }
        f32x4 acc1[4];
        #pragma unroll
        for (int tt = 0; tt < 4; ++tt) {
            f32x4 acc = b1f[tt];
            acc = __builtin_amdgcn_mfma_f32_16x16x32_f16(asH(c1b0), asH(rd[tt]), acc, 0, 0, 0);
            acc = __builtin_amdgcn_mfma_f32_16x16x32_f16(asH(c1b1), asH(rd[tt + 1]), acc, 0, 0, 0);
            acc1[tt] = acc;
        }

        // conv1 epilogue: rows=oc in regs, col=pos -> b64 swizzled writes
        #pragma unroll
        for (int tt = 0; tt < 4; ++tt) {
            const int pos = (2 * tt + (m >> 3) + 2) * 12 + (m & 7) + 2;
            const int off = ((pos << 5) + ch * 8) ^ ((pos & 12) << 2);
            unsigned int w0 = pkr(acc1[tt][0], acc1[tt][1]);
            unsigned int w1 = pkr(acc1[tt][2], acc1[tt][3]);
            *(uint2*)(base + off) = make_uint2(w0, w1);
        }

        // zero h1c pad rings — EVERY pass (ring entries overlap the xs bytes
        // that the x-interior write just repopulated; see header note)
        {
            uint4 z; z.x = z.y = z.z = z.w = 0u;
            #pragma unroll
            for (int k2 = 0; k2 < 3; ++k2) {
                int idx = l + k2 * 64;          // 0..159
                if (idx < 160) {
                    int pi = idx >> 1, half = idx & 1;
                    int pos;
                    if (pi < 24) pos = pi;
                    else if (pi < 48) pos = pi + 96;
                    else {
                        int q = pi - 48;
                        int c = q & 3; c = (c < 2) ? c : c + 8;
                        pos = (2 + (q >> 2)) * 12 + c;
                    }
                    int off = ((pos << 5) + (half << 4)) ^ ((pos & 12) << 2);
                    *(uint4*)(base + off) = z;
                }
            }
        }

        // conv2: 13 b128 reads + 13 MFMA; h2 write XOR-swizzled by slot
        {
            f32x4 a = b2f;
            #pragma unroll
            for (int kk = 0; kk < 13; ++kk) {
                uint4 r0 = *(const uint4*)(base + c2off[kk]);
                a = __builtin_amdgcn_mfma_f32_16x16x32_f16(asH(c2b[kk]), asH(r0), a, 0, 0, 0);
            }
            if (ch < 3) {
                const int slot = wave * 2 + s;
                const int off = m * 24 + ch * 8;
                unsigned int w0 = pkr(a[0], a[1]);
                unsigned int w1 = pkr(a[2], a[3]);
                *(uint2*)(L + H2B + slot * 384 + (off ^ (slot << 4))) = make_uint2(w0, w1);
            }
        }
    }

    // prefetch fc1 frags (waves 0,1 only; nt = wave)
    uint4 afc[6];
    if (wave < 2) {
        #pragma unroll
        for (int kk = 0; kk < 6; ++kk) afc[kk] = fr[(15 + wave * 6 + kk) * 64 + l];
    }

    __syncthreads();

    // fc1: rows = fc cols (regs), cols = 8 samples (slot = m&7, swizzled read)
    if (wave < 2) {
        const int nt = wave;
        const int slot = m & 7;
        f32x4 acc;
        #pragma unroll
        for (int r = 0; r < 4; ++r) acc[r] = wsf[WS_B3 + (nt * 4 + r) * 64 + l];
        #pragma unroll
        for (int kk = 0; kk < 6; ++kk) {
            uint4 bb = *(const uint4*)(L + H2B + slot * 384 +
                                       ((kk * 64 + ch * 16) ^ (slot << 4)));
            acc = __builtin_amdgcn_mfma_f32_16x16x32_f16(asH(afc[kk]), asH(bb), acc, 0, 0, 0);
        }
        if (m < 8) {
            unsigned int w0 = pkr(acc[0], acc[1]);
            unsigned int w1 = pkr(acc[2], acc[3]);
            *(uint2*)(L + H3B + m * 64 + nt * 32 + ch * 8) = make_uint2(w0, w1);
        }
    }

    __syncthreads();

    // fc2: wave 0 only, 1 MFMA for all 8 samples
    if (wave == 0) {
        uint4 aw = fr[27 * 64 + l];
        uint4 bb = *(const uint4*)(L + H3B + (m & 7) * 64 + ch * 16);
        f32x4 acc;
        #pragma unroll
        for (int r = 0; r < 4; ++r) acc[r] = wsf[WS_B4 + r * 64 + l];
        acc = __builtin_amdgcn_mfma_f32_16x16x32_f16(asH(aw), asH(bb), acc, 0, 0, 0);
        if (m < 8) {
            float* op = out + (size_t)(sblk + m) * 10 + 4 * ch;
            if (ch < 2) {
                *(float2*)op       = make_float2(acc[0], acc[1]);
                *(float2*)(op + 2) = make_float2(acc[2], acc[3]);
            } else if (ch == 2) {
                *(float2*)op       = make_float2(acc[0], acc[1]);
            }
        }
    }
}

extern "C" void kernel_launch(void* const* d_in, const int* in_sizes, int n_in,
                              void* d_out, int out_size, void* d_ws, size_t ws_size,
                              hipStream_t stream) {
    const float* x    = (const float*)d_in[0];
    const float* H1w  = (const float*)d_in[1];
    const float* H1b  = (const float*)d_in[2];
    const float* H2w  = (const float*)d_in[3];
    const float* H2b  = (const float*)d_in[4];
    const float* H3w  = (const float*)d_in[5];
    const float* H3b  = (const float*)d_in[6];
    const float* outw = (const float*)d_in[7];
    const float* outb = (const float*)d_in[8];
    float* outp = (float*)d_out;
    unsigned int* ws = (unsigned int*)d_ws;

    build_tables<<<30, 256, 0, stream>>>(H1w, H1b, H2w, H2b, H3w, H3b, outw, outb, ws);

    const int B = in_sizes[0] / 256;          // 131072
    const int blocks = B / 8;                 // 16384
    modernnet_mfma<<<blocks, 256, 0, stream>>>(x, ws, outp);
}

// Round 11
// 102.154 us; speedup vs baseline: 4.2645x; 4.2645x over previous
//
#include <hip/hip_runtime.h>
#include <hip/hip_fp16.h>

typedef _Float16 f16x8 __attribute__((ext_vector_type(8)));
typedef float f32x4 __attribute__((ext_vector_type(4)));

union U4H8 { uint4 u; f16x8 h; };
__device__ inline f16x8 asH(uint4 u){ U4H8 x; x.u = u; return x.h; }
__device__ inline unsigned int pk(float a, float b){
    __half2 h = __floats2half2_rn(a, b);
    union { __half2 h; unsigned int u; } c; c.h = h; return c.u;
}
// pack two floats to f16 with relu
__device__ inline unsigned int pkr(float a, float b){
    return pk(fmaxf(a, 0.f), fmaxf(b, 0.f));
}
__device__ inline unsigned short h16(float a){
    union { __half h; unsigned short s; } c; c.h = __float2half(a); return c.s;
}

// ws dword layout: frags uint4[28][64] = dwords [0,7168);
// b1f f32[16][64] @7168 | b2f f32[4][64] @8192 | b3f f32[8][64] @8448 |
// b4f f32[4][64] @8960 ; end 9216 dwords (36 KiB).
#define NFRAG 28
#define WS_B1 7168
#define WS_B2 8192
#define WS_B3 8448
#define WS_B4 8960

// frag fi: 0-1 conv1 (k=kh*8+kw, rows=oc); 2-14 conv2 (k=tap*16+ic, rows=oc);
//          15-26 fc1 (nt*6+kk, k=pos*12+oc2, rows=fc-col); 27 fc2 (rows=logit)
__global__ __launch_bounds__(256) void build_tables(
    const float* __restrict__ H1w, const float* __restrict__ H1b,
    const float* __restrict__ H2w, const float* __restrict__ H2b,
    const float* __restrict__ H3w, const float* __restrict__ H3b,
    const float* __restrict__ outw, const float* __restrict__ outb,
    unsigned int* __restrict__ ws)
{
    const int t = threadIdx.x, b = blockIdx.x;
    float* wsf = (float*)ws;

    if (b < NFRAG) {
        if (t < 64) {
            const int lane = t, ch = lane >> 4, oc = lane & 15;
            const int fi = b;
            unsigned short us[8];
            for (int j = 0; j < 8; ++j) {
                float w = 0.f;
                if (fi < 2) {                         // conv1
                    int kh = fi * 4 + ch;
                    if (kh < 5 && j < 5 && oc < 12) w = H1w[oc * 25 + kh * 5 + j];
                } else if (fi < 15) {                 // conv2 channels-last
                    int kk = fi - 2;
                    int tap = kk * 2 + (ch >> 1);
                    int ic = (ch & 1) * 8 + j;
                    if (tap < 25 && oc < 12) {
                        int kh = tap / 5, kw = tap % 5;
                        int q = oc >> 2, icl = -1;
                        if (q == 0)      { if (ic < 8) icl = ic; }
                        else if (q == 1) { if (ic >= 4 && ic < 12) icl = ic - 4; }
                        else             { if (ic < 4) icl = ic;
                                           else if (ic >= 8 && ic < 12) icl = ic - 4; }
                        if (icl >= 0) w = H2w[((oc * 8 + icl) * 5 + kh) * 5 + kw];
                    }
                } else if (fi < 27) {                 // fc1 (k = pos*12+oc2)
                    int idx = fi - 15, nt = idx / 6, kk = idx % 6;
                    int k = kk * 32 + ch * 8 + j;     // 0..191
                    int pos = k / 12, oc2 = k % 12;
                    int col = nt * 16 + oc;
                    if (col < 30) w = H3w[(oc2 * 16 + pos) * 30 + col];
                } else {                              // fc2
                    int k = ch * 8 + j;
                    if (k < 30 && oc < 10) w = outw[k * 10 + oc];
                }
                us[j] = h16(w);
            }
            uint4 u;
            u.x = us[0] | ((unsigned int)us[1] << 16);
            u.y = us[2] | ((unsigned int)us[3] << 16);
            u.z = us[4] | ((unsigned int)us[5] << 16);
            u.w = us[6] | ((unsigned int)us[7] << 16);
            ((uint4*)ws)[fi * 64 + lane] = u;
        }
    } else if (b == NFRAG) {        // b1f: entry e=tt*4+r, lane(ch,m); oc=4ch+r
        for (int idx = t; idx < 1024; idx += 256) {
            int e = idx >> 6, l2 = idx & 63;
            int tt = e >> 2, r = e & 3;
            int oc = 4 * (l2 >> 4) + r, m2 = l2 & 15;
            int oh = 2 * tt + (m2 >> 3), ow = m2 & 7;
            float v = 0.f;
            if (oc < 12) {
                v = H1b[oc * 64 + oh * 8 + ow];
                for (int kh = 0; kh < 5; ++kh)
                    for (int kw = 0; kw < 5; ++kw) {
                        int rr = 2 * oh + kh, cc = 2 * ow + kw;
                        if (rr < 2 || rr >= 18 || cc < 2 || cc >= 18)
                            v -= H1w[oc * 25 + kh * 5 + kw];
                    }
            }
            wsf[WS_B1 + e * 64 + l2] = v;
        }
    } else {                        // b2f + b3f + b4f
        {
            int e = t >> 6, l2 = t & 63;
            int oc = 4 * (l2 >> 4) + e, m2 = l2 & 15;
            int oh = m2 >> 2, ow = m2 & 3;
            float v = 0.f;
            if (oc < 12) {
                v = H2b[oc * 16 + oh * 4 + ow];
                for (int icl = 0; icl < 8; ++icl)
                    for (int kh = 0; kh < 5; ++kh)
                        for (int kw = 0; kw < 5; ++kw) {
                            int rr = 2 * oh + kh - 2, cc = 2 * ow + kw - 2;
                            if (rr < 0 || rr >= 8 || cc < 0 || cc >= 8)
                                v -= H2w[((oc * 8 + icl) * 5 + kh) * 5 + kw];
                        }
            }
            wsf[WS_B2 + e * 64 + l2] = v;
        }
        for (int i = t; i < 512; i += 256) {    // b3f: e = nt*4+r
            int e = i >> 6, l2 = i & 63;
            int nt = e >> 2, r = e & 3, ch = l2 >> 4;
            int j = nt * 16 + 4 * ch + r;
            wsf[WS_B3 + e * 64 + l2] = (j < 30) ? H3b[j] : 0.f;
        }
        {                                        // b4f: e = r
            int e = t >> 6, l2 = t & 63, ch = l2 >> 4;
            int j = 4 * ch + e;
            wsf[WS_B4 + e * 64 + l2] = (j < 10) ? outb[j] : 0.f;
        }
    }
}

// ---------------- main kernel ----------------
// Block LDS (22016 B) -> 7 blocks/CU (LDS-bound occupancy):
//   per-wave region @ wave*4608 : ONE sample's h1c [144 pos][16 ch] half,
//     XOR-swizzled; processed twice (sample pass s=0,1). xs overlay @ bytes
//     0..960 of the region (dead after conv1 reads).
//   Pad ring re-zeroed EVERY pass (the x-interior write covers bytes
//   100..852 which contain swizzled ring entries — R9 bug).
//   shared h2 @ 18432 : 8 slots x 384 B, XOR-swizzled by slot
//   shared h3 @ 21504 : 8 slots x 64 B
// launch_bounds (256,4): cap 128 VGPR. (256,7) caused catastrophic spill
// (R10: VGPR=36, 2 GB scratch traffic, 500 us). LDS limits blocks/CU to 7;
// we reach it iff allocator lands <=73 VGPR (R8: 56 under identical cap).
#define H2B 18432
#define H3B 21504
__global__ __launch_bounds__(256, 4) void modernnet_mfma(
    const float* __restrict__ x, const unsigned int* __restrict__ ws,
    float* __restrict__ out)
{
    __shared__ uint4 lds4[1376];
    char* L = (char*)lds4;
    const int t = threadIdx.x, wave = t >> 6, l = t & 63;
    const int ch = l >> 4, m = l & 15;
    char* base = L + wave * 4608;
    const int sblk = blockIdx.x * 8;
    const int s0 = sblk + wave * 2;

    const uint4* fr = (const uint4*)ws;
    const float* wsf = (const float*)ws;

    // prefetch global x for both samples (hide HBM latency under frag loads)
    float4 xv0 = *(const float4*)(x + (size_t)(s0 + 0) * 256 + l * 4);
    float4 xv1 = *(const float4*)(x + (size_t)(s0 + 1) * 256 + l * 4);

    // conv1 weight + bias frags
    uint4 c1b0 = fr[0 * 64 + l], c1b1 = fr[1 * 64 + l];
    f32x4 b1f[4];
    #pragma unroll
    for (int tt = 0; tt < 4; ++tt)
        #pragma unroll
        for (int r = 0; r < 4; ++r) b1f[tt][r] = wsf[WS_B1 + (tt * 4 + r) * 64 + l];

    // conv2 per-lane read offsets — compile-time tap table, no divides
    int c2off[13];
    {
        const int mb = 24 * (m >> 2) + 2 * (m & 3);
        const int hb = (ch & 1) << 4;
        const int sel = (ch >> 1) & 1;
        #pragma unroll
        for (int kk = 0; kk < 13; ++kk) {
            const int t0 = 2 * kk;
            const int t1 = (2 * kk + 1 <= 24) ? 2 * kk + 1 : 24;
            const int p0 = (t0 / 5) * 12 + (t0 % 5);
            const int p1 = (t1 / 5) * 12 + (t1 % 5);
            int pos = mb + (sel ? p1 : p0);
            c2off[kk] = ((pos << 5) + hb) ^ ((pos & 12) << 2);
        }
    }

    // conv2 weights + bias (held across both passes)
    uint4 c2b[13];
    #pragma unroll
    for (int kk = 0; kk < 13; ++kk) c2b[kk] = fr[(2 + kk) * 64 + l];
    f32x4 b2f;
    #pragma unroll
    for (int r = 0; r < 4; ++r) b2f[r] = wsf[WS_B2 + r * 64 + l];

    // -------- two sample passes through the same 4608-B region --------
    #pragma unroll
    for (int s = 0; s < 2; ++s) {
        // zero xs overlay (bytes 0..960): rows 0-19 x 24 cols, f16 zeros
        {
            uint4 z; z.x = z.y = z.z = z.w = 0u;
            if (l < 60) ((uint4*)base)[l] = z;
        }
        // write x interior (16x16) -> f16, rows 2-17 cols 2-17
        {
            const float4 v = (s == 0) ? xv0 : xv1;
            const int r = l >> 2, c = (l & 3) * 4;
            char* dst = base + (r + 2) * 48 + (c + 2) * 2;
            ((unsigned int*)dst)[0] = pk(v.x, v.y);
            ((unsigned int*)dst)[1] = pk(v.z, v.w);
        }

        // conv1: 5 b128 reads. rd[i] (i<4) = rows 4i+2h+ch (h=m>>3);
        // tile tt: kh0-3 operand = rd[tt], kh4 operand = rd[tt+1] (only ch=0
        // lanes carry nonzero c1b1 weights; their rows = 4tt+2h+4 = correct).
        // rd[4] read wave-uniform row 16+2h (ch>0 rows would be OOB junk).
        uint4 rd[5];
        #pragma unroll
        for (int i = 0; i < 5; ++i) {
            const int cho = (i < 4) ? ch * 48 : 0;
            const unsigned int* p = (const unsigned int*)
                (base + (2 * i + (m >> 3)) * 96 + (m & 7) * 4 + cho);
            rd[i] = make_uint4(p[0], p[1], p[2], p[3]);
        }
        f32x4 acc1[4];
        #pragma unroll
        for (int tt = 0; tt < 4; ++tt) {
            f32x4 acc = b1f[tt];
            acc = __builtin_amdgcn_mfma_f32_16x16x32_f16(asH(c1b0), asH(rd[tt]), acc, 0, 0, 0);
            acc = __builtin_amdgcn_mfma_f32_16x16x32_f16(asH(c1b1), asH(rd[tt + 1]), acc, 0, 0, 0);
            acc1[tt] = acc;
        }

        // conv1 epilogue: rows=oc in regs, col=pos -> b64 swizzled writes
        #pragma unroll
        for (int tt = 0; tt < 4; ++tt) {
            const int pos = (2 * tt + (m >> 3) + 2) * 12 + (m & 7) + 2;
            const int off = ((pos << 5) + ch * 8) ^ ((pos & 12) << 2);
            unsigned int w0 = pkr(acc1[tt][0], acc1[tt][1]);
            unsigned int w1 = pkr(acc1[tt][2], acc1[tt][3]);
            *(uint2*)(base + off) = make_uint2(w0, w1);
        }

        // zero h1c pad rings — EVERY pass (ring entries overlap the xs bytes
        // that the x-interior write just repopulated)
        {
            uint4 z; z.x = z.y = z.z = z.w = 0u;
            #pragma unroll
            for (int k2 = 0; k2 < 3; ++k2) {
                int idx = l + k2 * 64;          // 0..159
                if (idx < 160) {
                    int pi = idx >> 1, half = idx & 1;
                    int pos;
                    if (pi < 24) pos = pi;
                    else if (pi < 48) pos = pi + 96;
                    else {
                        int q = pi - 48;
                        int c = q & 3; c = (c < 2) ? c : c + 8;
                        pos = (2 + (q >> 2)) * 12 + c;
                    }
                    int off = ((pos << 5) + (half << 4)) ^ ((pos & 12) << 2);
                    *(uint4*)(base + off) = z;
                }
            }
        }

        // conv2: 13 b128 reads + 13 MFMA; h2 write XOR-swizzled by slot
        {
            f32x4 a = b2f;
            #pragma unroll
            for (int kk = 0; kk < 13; ++kk) {
                uint4 r0 = *(const uint4*)(base + c2off[kk]);
                a = __builtin_amdgcn_mfma_f32_16x16x32_f16(asH(c2b[kk]), asH(r0), a, 0, 0, 0);
            }
            if (ch < 3) {
                const int slot = wave * 2 + s;
                const int off = m * 24 + ch * 8;
                unsigned int w0 = pkr(a[0], a[1]);
                unsigned int w1 = pkr(a[2], a[3]);
                *(uint2*)(L + H2B + slot * 384 + (off ^ (slot << 4))) = make_uint2(w0, w1);
            }
        }
    }

    // prefetch fc1 frags (waves 0,1 only; nt = wave)
    uint4 afc[6];
    if (wave < 2) {
        #pragma unroll
        for (int kk = 0; kk < 6; ++kk) afc[kk] = fr[(15 + wave * 6 + kk) * 64 + l];
    }

    __syncthreads();

    // fc1: rows = fc cols (regs), cols = 8 samples (slot = m&7, swizzled read)
    if (wave < 2) {
        const int nt = wave;
        const int slot = m & 7;
        f32x4 acc;
        #pragma unroll
        for (int r = 0; r < 4; ++r) acc[r] = wsf[WS_B3 + (nt * 4 + r) * 64 + l];
        #pragma unroll
        for (int kk = 0; kk < 6; ++kk) {
            uint4 bb = *(const uint4*)(L + H2B + slot * 384 +
                                       ((kk * 64 + ch * 16) ^ (slot << 4)));
            acc = __builtin_amdgcn_mfma_f32_16x16x32_f16(asH(afc[kk]), asH(bb), acc, 0, 0, 0);
        }
        if (m < 8) {
            unsigned int w0 = pkr(acc[0], acc[1]);
            unsigned int w1 = pkr(acc[2], acc[3]);
            *(uint2*)(L + H3B + m * 64 + nt * 32 + ch * 8) = make_uint2(w0, w1);
        }
    }

    __syncthreads();

    // fc2: wave 0 only, 1 MFMA for all 8 samples
    if (wave == 0) {
        uint4 aw = fr[27 * 64 + l];
        uint4 bb = *(const uint4*)(L + H3B + (m & 7) * 64 + ch * 16);
        f32x4 acc;
        #pragma unroll
        for (int r = 0; r < 4; ++r) acc[r] = wsf[WS_B4 + r * 64 + l];
        acc = __builtin_amdgcn_mfma_f32_16x16x32_f16(asH(aw), asH(bb), acc, 0, 0, 0);
        if (m < 8) {
            float* op = out + (size_t)(sblk + m) * 10 + 4 * ch;
            if (ch < 2) {
                *(float2*)op       = make_float2(acc[0], acc[1]);
                *(float2*)(op + 2) = make_float2(acc[2], acc[3]);
            } else if (ch == 2) {
                *(float2*)op       = make_float2(acc[0], acc[1]);
            }
        }
    }
}

extern "C" void kernel_launch(void* const* d_in, const int* in_sizes, int n_in,
                              void* d_out, int out_size, void* d_ws, size_t ws_size,
                              hipStream_t stream) {
    const float* x    = (const float*)d_in[0];
    const float* H1w  = (const float*)d_in[1];
    const float* H1b  = (const float*)d_in[2];
    const float* H2w  = (const float*)d_in[3];
    const float* H2b  = (const float*)d_in[4];
    const float* H3w  = (const float*)d_in[5];
    const float* H3b  = (const float*)d_in[6];
    const float* outw = (const float*)d_in[7];
    const float* outb = (const float*)d_in[8];
    float* outp = (float*)d_out;
    unsigned int* ws = (unsigned int*)d_ws;

    build_tables<<<30, 256, 0, stream>>>(H1w, H1b, H2w, H2b, H3w, H3b, outw, outb, ws);

    const int B = in_sizes[0] / 256;          // 131072
    const int blocks = B / 8;                 // 16384
    modernnet_mfma<<<blocks, 256, 0, stream>>>(x, ws, outp);
}

// Round 12
// 98.494 us; speedup vs baseline: 4.4230x; 1.0372x over previous
//
#include <hip/hip_runtime.h>
#include <hip/hip_fp16.h>

typedef _Float16 f16x8 __attribute__((ext_vector_type(8)));
typedef float f32x4 __attribute__((ext_vector_type(4)));

union U4H8 { uint4 u; f16x8 h; };
__device__ inline f16x8 asH(uint4 u){ U4H8 x; x.u = u; return x.h; }
__device__ inline unsigned int pk(float a, float b){
    __half2 h = __floats2half2_rn(a, b);
    union { __half2 h; unsigned int u; } c; c.h = h; return c.u;
}
__device__ inline unsigned int pkr(float a, float b){
    return pk(fmaxf(a, 0.f), fmaxf(b, 0.f));
}
__device__ inline unsigned short h16(float a){
    union { __half h; unsigned short s; } c; c.h = __float2half(a); return c.s;
}

// ws dword layout: frags uint4[28][64] = dwords [0,7168);
// b1f f32[16][64] @7168 | b2f f32[4][64] @8192 | b3f f32[8][64] @8448 |
// b4f f32[4][64] @8960 ; end 9216 dwords (36 KiB).
#define NFRAG 28
#define WS_B1 7168
#define WS_B2 8192
#define WS_B3 8448
#define WS_B4 8960

// frag fi: 0-1 conv1 (k=kh*8+kw, rows=oc); 2-14 conv2 (k=tap*16+ic, rows=oc;
//          ic>=12 weights are ZERO — the A-side may feed garbage there);
//          15-26 fc1 (nt*6+kk, k=pos*12+oc2, rows=fc-col); 27 fc2 (rows=logit)
__global__ __launch_bounds__(256) void build_tables(
    const float* __restrict__ H1w, const float* __restrict__ H1b,
    const float* __restrict__ H2w, const float* __restrict__ H2b,
    const float* __restrict__ H3w, const float* __restrict__ H3b,
    const float* __restrict__ outw, const float* __restrict__ outb,
    unsigned int* __restrict__ ws)
{
    const int t = threadIdx.x, b = blockIdx.x;
    float* wsf = (float*)ws;

    if (b < NFRAG) {
        if (t < 64) {
            const int lane = t, ch = lane >> 4, oc = lane & 15;
            const int fi = b;
            unsigned short us[8];
            for (int j = 0; j < 8; ++j) {
                float w = 0.f;
                if (fi < 2) {                         // conv1
                    int kh = fi * 4 + ch;
                    if (kh < 5 && j < 5 && oc < 12) w = H1w[oc * 25 + kh * 5 + j];
                } else if (fi < 15) {                 // conv2 channels-last
                    int kk = fi - 2;
                    int tap = kk * 2 + (ch >> 1);
                    int ic = (ch & 1) * 8 + j;
                    if (tap < 25 && oc < 12) {
                        int kh = tap / 5, kw = tap % 5;
                        int q = oc >> 2, icl = -1;
                        if (q == 0)      { if (ic < 8) icl = ic; }
                        else if (q == 1) { if (ic >= 4 && ic < 12) icl = ic - 4; }
                        else             { if (ic < 4) icl = ic;
                                           else if (ic >= 8 && ic < 12) icl = ic - 4; }
                        if (icl >= 0) w = H2w[((oc * 8 + icl) * 5 + kh) * 5 + kw];
                    }
                } else if (fi < 27) {                 // fc1 (k = pos*12+oc2)
                    int idx = fi - 15, nt = idx / 6, kk = idx % 6;
                    int k = kk * 32 + ch * 8 + j;     // 0..191
                    int pos = k / 12, oc2 = k % 12;
                    int col = nt * 16 + oc;
                    if (col < 30) w = H3w[(oc2 * 16 + pos) * 30 + col];
                } else {                              // fc2
                    int k = ch * 8 + j;
                    if (k < 30 && oc < 10) w = outw[k * 10 + oc];
                }
                us[j] = h16(w);
            }
            uint4 u;
            u.x = us[0] | ((unsigned int)us[1] << 16);
            u.y = us[2] | ((unsigned int)us[3] << 16);
            u.z = us[4] | ((unsigned int)us[5] << 16);
            u.w = us[6] | ((unsigned int)us[7] << 16);
            ((uint4*)ws)[fi * 64 + lane] = u;
        }
    } else if (b == NFRAG) {        // b1f: entry e=tt*4+r, lane(ch,m); oc=4ch+r
        for (int idx = t; idx < 1024; idx += 256) {
            int e = idx >> 6, l2 = idx & 63;
            int tt = e >> 2, r = e & 3;
            int oc = 4 * (l2 >> 4) + r, m2 = l2 & 15;
            int oh = 2 * tt + (m2 >> 3), ow = m2 & 7;
            float v = 0.f;
            if (oc < 12) {
                v = H1b[oc * 64 + oh * 8 + ow];
                for (int kh = 0; kh < 5; ++kh)
                    for (int kw = 0; kw < 5; ++kw) {
                        int rr = 2 * oh + kh, cc = 2 * ow + kw;
                        if (rr < 2 || rr >= 18 || cc < 2 || cc >= 18)
                            v -= H1w[oc * 25 + kh * 5 + kw];
                    }
            }
            wsf[WS_B1 + e * 64 + l2] = v;
        }
    } else {                        // b2f + b3f + b4f
        {
            int e = t >> 6, l2 = t & 63;
            int oc = 4 * (l2 >> 4) + e, m2 = l2 & 15;
            int oh = m2 >> 2, ow = m2 & 3;
            float v = 0.f;
            if (oc < 12) {
                v = H2b[oc * 16 + oh * 4 + ow];
                for (int icl = 0; icl < 8; ++icl)
                    for (int kh = 0; kh < 5; ++kh)
                        for (int kw = 0; kw < 5; ++kw) {
                            int rr = 2 * oh + kh - 2, cc = 2 * ow + kw - 2;
                            if (rr < 0 || rr >= 8 || cc < 0 || cc >= 8)
                                v -= H2w[((oc * 8 + icl) * 5 + kh) * 5 + kw];
                        }
            }
            wsf[WS_B2 + e * 64 + l2] = v;
        }
        for (int i = t; i < 512; i += 256) {    // b3f: e = nt*4+r
            int e = i >> 6, l2 = i & 63;
            int nt = e >> 2, r = e & 3, ch = l2 >> 4;
            int j = nt * 16 + 4 * ch + r;
            wsf[WS_B3 + e * 64 + l2] = (j < 30) ? H3b[j] : 0.f;
        }
        {                                        // b4f: e = r
            int e = t >> 6, l2 = t & 63, ch = l2 >> 4;
            int j = 4 * ch + e;
            wsf[WS_B4 + e * 64 + l2] = (j < 10) ? outb[j] : 0.f;
        }
    }
}

// ---------------- main kernel ----------------
// R8 interleaved structure (2 samples/wave computed together for ILP) with a
// 12-channel h1c layout: [144 pos][12 ch] half = 24 B/pos, 3456 B/sample.
// The conv2 odd-group read (k-slots 8-15) fetches 16 B at pos*24+16: ic8-11
// real + 8 B of the NEXT position's ic0-3 — garbage that hits ZERO weights
// (frag table has w=0 for ic>=12), so it is numerically inert. 24 B stride
// is only 8-aligned -> conv2 reads are 2x ds_read_b64 (same LDS-pipe cycles
// as 1x b128). No h1c XOR swizzle (6-dword stride self-spreads banks).
// Block LDS = 4 waves x 6912 + h2 3072 + h3 512 = 31232 B -> 5 blocks/CU
// (20 waves/CU, +25% vs R8's 4 blocks at 40448 B).
// launch_bounds (256,4): cap 128 VGPR. (256,7) caused catastrophic spill
// (R10: VGPR=36, 2 GB scratch). Actual VGPR ~60 <= 102 -> 5 blocks reachable.
#define REG   3456
#define H2B   27648
#define H3B   30720
__global__ __launch_bounds__(256, 4) void modernnet_mfma(
    const float* __restrict__ x, const unsigned int* __restrict__ ws,
    float* __restrict__ out)
{
    __shared__ uint4 lds4[1952];
    char* L = (char*)lds4;
    const int t = threadIdx.x, wave = t >> 6, l = t & 63;
    const int ch = l >> 4, m = l & 15;
    char* base = L + wave * (2 * REG);
    const int sblk = blockIdx.x * 8;
    const int s0 = sblk + wave * 2;

    const uint4* fr = (const uint4*)ws;
    const float* wsf = (const float*)ws;

    // hoisted global x loads (2 samples, 8 floats/lane) — overlap frag loads
    const float* xp = x + (size_t)s0 * 256 + l * 8;
    float4 xv0 = *(const float4*)xp;
    float4 xv1 = *(const float4*)(xp + 4);

    // conv1 weight + bias frags
    uint4 c1b0 = fr[0 * 64 + l], c1b1 = fr[1 * 64 + l];
    f32x4 b1f[4];
    #pragma unroll
    for (int tt = 0; tt < 4; ++tt)
        #pragma unroll
        for (int r = 0; r < 4; ++r) b1f[tt][r] = wsf[WS_B1 + (tt * 4 + r) * 64 + l];

    // conv2 per-lane read offsets (24 B/pos, odd ch-group +16)
    int c2off[13];
    {
        const int mb = 24 * (m >> 2) + 2 * (m & 3);
        const int hb = (ch & 1) << 4;
        const int sel = (ch >> 1) & 1;
        #pragma unroll
        for (int kk = 0; kk < 13; ++kk) {
            const int t0 = 2 * kk;
            const int t1 = (2 * kk + 1 <= 24) ? 2 * kk + 1 : 24;
            const int p0 = (t0 / 5) * 12 + (t0 % 5);
            const int p1 = (t1 / 5) * 12 + (t1 % 5);
            int pos = mb + (sel ? p1 : p0);
            c2off[kk] = pos * 24 + hb;
        }
    }

    // conv2 weights + bias
    uint4 c2b[13];
    #pragma unroll
    for (int kk = 0; kk < 13; ++kk) c2b[kk] = fr[(2 + kk) * 64 + l];
    f32x4 b2f;
    #pragma unroll
    for (int r = 0; r < 4; ++r) b2f[r] = wsf[WS_B2 + r * 64 + l];

    // zero xs overlays (bytes [0,960) of each region)
    {
        uint4 z; z.x = z.y = z.z = z.w = 0u;
        if (l < 60) {
            ((uint4*)base)[l] = z;
            *(uint4*)(base + REG + l * 16) = z;
        }
    }

    // write x interior (2 samples x 16x16) -> f16 at each region base
    {
        int sI = l >> 5, idx = l & 31;
        int r = idx >> 1, c = (idx & 1) * 8;
        const float4 va = sI ? xv1 : xv0;
        const float4 vb = sI ? *(const float4*)(xp + 4) : xv0;  // (unused dup guard)
        (void)vb;
        char* dst = base + sI * REG + (r + 2) * 48 + (c + 2) * 2;
        const float4 v0 = sI ? xv1 : xv0;
        (void)va;
        // lane covers 8 consecutive floats = cols c..c+7 of row r
        ((unsigned int*)dst)[0] = pk(v0.x, v0.y);
        ((unsigned int*)dst)[1] = pk(v0.z, v0.w);
        float4 v1 = sI ? *(const float4*)(xp + 4) : *(const float4*)(xp + 4);
        // NOTE: lanes 0-31 hold sample0 floats in xv0/xv1; lanes 32-63 sample1.
        // xv0 = floats [l*8, l*8+4), xv1 = [l*8+4, l*8+8) of the PAIR region:
        // for lanes>=32 these already index into sample1. So v0=xv0, v1=xv1.
        (void)v1;
        ((unsigned int*)dst)[2] = pk(xv1.x, xv1.y);
        ((unsigned int*)dst)[3] = pk(xv1.z, xv1.w);
        // fix: first two words must come from xv0 regardless of sI
        ((unsigned int*)dst)[0] = pk(xv0.x, xv0.y);
        ((unsigned int*)dst)[1] = pk(xv0.z, xv0.w);
    }

    // conv1: 10 b128-equivalent reads (both samples), then 16 MFMAs, then
    // epilogue writes — all xs reads precede all h1c writes (overlay safety).
    uint4 rd[2][5];
    #pragma unroll
    for (int s = 0; s < 2; ++s)
        #pragma unroll
        for (int i = 0; i < 5; ++i) {
            const int cho = (i < 4) ? ch * 48 : 0;   // rd[4]: wave-uniform row
            const unsigned int* p = (const unsigned int*)
                (base + s * REG + (2 * i + (m >> 3)) * 96 + (m & 7) * 4 + cho);
            rd[s][i] = make_uint4(p[0], p[1], p[2], p[3]);
        }
    f32x4 acc1[8];
    #pragma unroll
    for (int i = 0; i < 8; ++i) {
        const int s = i >> 2, tt = i & 3;
        f32x4 acc = b1f[tt];
        acc = __builtin_amdgcn_mfma_f32_16x16x32_f16(asH(c1b0), asH(rd[s][tt]), acc, 0, 0, 0);
        acc = __builtin_amdgcn_mfma_f32_16x16x32_f16(asH(c1b1), asH(rd[s][tt + 1]), acc, 0, 0, 0);
        acc1[i] = acc;
    }

    // conv1 epilogue: rows=oc in regs, col=pos -> b64 writes (ch<3: oc 0-11)
    #pragma unroll
    for (int i = 0; i < 8; ++i) {
        const int s = i >> 2, tt = i & 3;
        if (ch < 3) {
            const int pos = (2 * tt + (m >> 3) + 2) * 12 + (m & 7) + 2;
            unsigned int w0 = pkr(acc1[i][0], acc1[i][1]);
            unsigned int w1 = pkr(acc1[i][2], acc1[i][3]);
            *(uint2*)(base + s * REG + pos * 24 + ch * 8) = make_uint2(w0, w1);
        }
    }

    // zero h1c pad rings (both samples): 120 x 16B chunks per sample
    {
        uint4 z; z.x = z.y = z.z = z.w = 0u;
        #pragma unroll
        for (int k2 = 0; k2 < 4; ++k2) {
            int idx = l + k2 * 64;               // 0..255, use 0..239
            if (idx < 240) {
                int smp = (idx >= 120) ? 1 : 0;
                int i1 = idx - smp * 120;
                int off;
                if (i1 < 36)      off = i1 * 16;                 // rows 0-1
                else if (i1 < 72) off = 2880 + (i1 - 36) * 16;   // rows 10-11
                else {                                           // side cols
                    int q = i1 - 72;                             // 0..47
                    int row = 2 + q / 6, c6 = q % 6;
                    off = row * 288 + (c6 < 3 ? c6 * 16 : 192 + c6 * 16);
                }
                *(uint4*)(base + smp * REG + off) = z;
            }
        }
    }

    // conv2: two interleaved acc chains (ILP); reads = 2x ds_read_b64 each
    {
        const char* h0 = base;
        const char* h1 = base + REG;
        f32x4 a0 = b2f, a1 = b2f;
        #pragma unroll
        for (int kk = 0; kk < 13; ++kk) {
            uint2 r0a = *(const uint2*)(h0 + c2off[kk]);
            uint2 r0b = *(const uint2*)(h0 + c2off[kk] + 8);
            uint2 r1a = *(const uint2*)(h1 + c2off[kk]);
            uint2 r1b = *(const uint2*)(h1 + c2off[kk] + 8);
            uint4 r0 = make_uint4(r0a.x, r0a.y, r0b.x, r0b.y);
            uint4 r1 = make_uint4(r1a.x, r1a.y, r1b.x, r1b.y);
            a0 = __builtin_amdgcn_mfma_f32_16x16x32_f16(asH(c2b[kk]), asH(r0), a0, 0, 0, 0);
            a1 = __builtin_amdgcn_mfma_f32_16x16x32_f16(asH(c2b[kk]), asH(r1), a1, 0, 0, 0);
        }
        if (ch < 3) {
            const int sl0 = wave * 2, sl1 = wave * 2 + 1;
            const int off = m * 24 + ch * 8;
            unsigned int w0 = pkr(a0[0], a0[1]);
            unsigned int w1 = pkr(a0[2], a0[3]);
            *(uint2*)(L + H2B + sl0 * 384 + (off ^ (sl0 << 4))) = make_uint2(w0, w1);
            w0 = pkr(a1[0], a1[1]);
            w1 = pkr(a1[2], a1[3]);
            *(uint2*)(L + H2B + sl1 * 384 + (off ^ (sl1 << 4))) = make_uint2(w0, w1);
        }
    }

    // prefetch fc1 frags (waves 0,1; nt = wave)
    uint4 afc[6];
    if (wave < 2) {
        #pragma unroll
        for (int kk = 0; kk < 6; ++kk) afc[kk] = fr[(15 + wave * 6 + kk) * 64 + l];
    }

    __syncthreads();

    // fc1: rows = fc cols (regs), cols = 8 samples (slot = m&7, swizzled read)
    if (wave < 2) {
        const int nt = wave;
        const int slot = m & 7;
        f32x4 acc;
        #pragma unroll
        for (int r = 0; r < 4; ++r) acc[r] = wsf[WS_B3 + (nt * 4 + r) * 64 + l];
        #pragma unroll
        for (int kk = 0; kk < 6; ++kk) {
            uint4 bb = *(const uint4*)(L + H2B + slot * 384 +
                                       ((kk * 64 + ch * 16) ^ (slot << 4)));
            acc = __builtin_amdgcn_mfma_f32_16x16x32_f16(asH(afc[kk]), asH(bb), acc, 0, 0, 0);
        }
        if (m < 8) {
            unsigned int w0 = pkr(acc[0], acc[1]);
            unsigned int w1 = pkr(acc[2], acc[3]);
            *(uint2*)(L + H3B + m * 64 + nt * 32 + ch * 8) = make_uint2(w0, w1);
        }
    }

    __syncthreads();

    // fc2: wave 0 only, 1 MFMA for all 8 samples
    if (wave == 0) {
        uint4 aw = fr[27 * 64 + l];
        uint4 bb = *(const uint4*)(L + H3B + (m & 7) * 64 + ch * 16);
        f32x4 acc;
        #pragma unroll
        for (int r = 0; r < 4; ++r) acc[r] = wsf[WS_B4 + r * 64 + l];
        acc = __builtin_amdgcn_mfma_f32_16x16x32_f16(asH(aw), asH(bb), acc, 0, 0, 0);
        if (m < 8) {
            float* op = out + (size_t)(sblk + m) * 10 + 4 * ch;
            if (ch < 2) {
                *(float2*)op       = make_float2(acc[0], acc[1]);
                *(float2*)(op + 2) = make_float2(acc[2], acc[3]);
            } else if (ch == 2) {
                *(float2*)op       = make_float2(acc[0], acc[1]);
            }
        }
    }
}

extern "C" void kernel_launch(void* const* d_in, const int* in_sizes, int n_in,
                              void* d_out, int out_size, void* d_ws, size_t ws_size,
                              hipStream_t stream) {
    const float* x    = (const float*)d_in[0];
    const float* H1w  = (const float*)d_in[1];
    const float* H1b  = (const float*)d_in[2];
    const float* H2w  = (const float*)d_in[3];
    const float* H2b  = (const float*)d_in[4];
    const float* H3w  = (const float*)d_in[5];
    const float* H3b  = (const float*)d_in[6];
    const float* outw = (const float*)d_in[7];
    const float* outb = (const float*)d_in[8];
    float* outp = (float*)d_out;
    unsigned int* ws = (unsigned int*)d_ws;

    build_tables<<<30, 256, 0, stream>>>(H1w, H1b, H2w, H2b, H3w, H3b, outw, outb, ws);

    const int B = in_sizes[0] / 256;          // 131072
    const int blocks = B / 8;                 // 16384
    modernnet_mfma<<<blocks, 256, 0, stream>>>(x, ws, outp);
}

// Round 13
// 91.215 us; speedup vs baseline: 4.7759x; 1.0798x over previous
//
#include <hip/hip_runtime.h>
#include <hip/hip_fp16.h>

typedef _Float16 f16x8 __attribute__((ext_vector_type(8)));
typedef float f32x4 __attribute__((ext_vector_type(4)));

union U4H8 { uint4 u; f16x8 h; };
__device__ inline f16x8 asH(uint4 u){ U4H8 x; x.u = u; return x.h; }
__device__ inline unsigned int pk(float a, float b){
    __half2 h = __floats2half2_rn(a, b);
    union { __half2 h; unsigned int u; } c; c.h = h; return c.u;
}
__device__ inline unsigned int pkr(float a, float b){
    return pk(fmaxf(a, 0.f), fmaxf(b, 0.f));
}
__device__ inline unsigned short h16(float a){
    union { __half h; unsigned short s; } c; c.h = __float2half(a); return c.s;
}

// ws dword layout: frags uint4[28][64] = dwords [0,7168);
// b1f f32[16][64] @7168 | b2f f32[4][64] @8192 | b3f f32[8][64] @8448 |
// b4f f32[4][64] @8960 ; end 9216 dwords (36 KiB).
#define NFRAG 28
#define WS_B1 7168
#define WS_B2 8192
#define WS_B3 8448
#define WS_B4 8960

// frag fi: 0-1 conv1 (k=kh*8+kw, rows=oc); 2-14 conv2 (k=tap*16+ic, rows=oc);
//          15-26 fc1 (nt*6+kk, k=pos*12+oc2, rows=fc-col); 27 fc2 (rows=logit)
__global__ __launch_bounds__(256) void build_tables(
    const float* __restrict__ H1w, const float* __restrict__ H1b,
    const float* __restrict__ H2w, const float* __restrict__ H2b,
    const float* __restrict__ H3w, const float* __restrict__ H3b,
    const float* __restrict__ outw, const float* __restrict__ outb,
    unsigned int* __restrict__ ws)
{
    const int t = threadIdx.x, b = blockIdx.x;
    float* wsf = (float*)ws;

    if (b < NFRAG) {
        if (t < 64) {
            const int lane = t, ch = lane >> 4, oc = lane & 15;
            const int fi = b;
            unsigned short us[8];
            for (int j = 0; j < 8; ++j) {
                float w = 0.f;
                if (fi < 2) {                         // conv1
                    int kh = fi * 4 + ch;
                    if (kh < 5 && j < 5 && oc < 12) w = H1w[oc * 25 + kh * 5 + j];
                } else if (fi < 15) {                 // conv2 channels-last
                    int kk = fi - 2;
                    int tap = kk * 2 + (ch >> 1);
                    int ic = (ch & 1) * 8 + j;
                    if (tap < 25 && oc < 12) {
                        int kh = tap / 5, kw = tap % 5;
                        int q = oc >> 2, icl = -1;
                        if (q == 0)      { if (ic < 8) icl = ic; }
                        else if (q == 1) { if (ic >= 4 && ic < 12) icl = ic - 4; }
                        else             { if (ic < 4) icl = ic;
                                           else if (ic >= 8 && ic < 12) icl = ic - 4; }
                        if (icl >= 0) w = H2w[((oc * 8 + icl) * 5 + kh) * 5 + kw];
                    }
                } else if (fi < 27) {                 // fc1 (k = pos*12+oc2)
                    int idx = fi - 15, nt = idx / 6, kk = idx % 6;
                    int k = kk * 32 + ch * 8 + j;     // 0..191
                    int pos = k / 12, oc2 = k % 12;
                    int col = nt * 16 + oc;
                    if (col < 30) w = H3w[(oc2 * 16 + pos) * 30 + col];
                } else {                              // fc2
                    int k = ch * 8 + j;
                    if (k < 30 && oc < 10) w = outw[k * 10 + oc];
                }
                us[j] = h16(w);
            }
            uint4 u;
            u.x = us[0] | ((unsigned int)us[1] << 16);
            u.y = us[2] | ((unsigned int)us[3] << 16);
            u.z = us[4] | ((unsigned int)us[5] << 16);
            u.w = us[6] | ((unsigned int)us[7] << 16);
            ((uint4*)ws)[fi * 64 + lane] = u;
        }
    } else if (b == NFRAG) {        // b1f: entry e=tt*4+r, lane(ch,m); oc=4ch+r
        for (int idx = t; idx < 1024; idx += 256) {
            int e = idx >> 6, l2 = idx & 63;
            int tt = e >> 2, r = e & 3;
            int oc = 4 * (l2 >> 4) + r, m2 = l2 & 15;
            int oh = 2 * tt + (m2 >> 3), ow = m2 & 7;
            float v = 0.f;
            if (oc < 12) {
                v = H1b[oc * 64 + oh * 8 + ow];
                for (int kh = 0; kh < 5; ++kh)
                    for (int kw = 0; kw < 5; ++kw) {
                        int rr = 2 * oh + kh, cc = 2 * ow + kw;
                        if (rr < 2 || rr >= 18 || cc < 2 || cc >= 18)
                            v -= H1w[oc * 25 + kh * 5 + kw];
                    }
            }
            wsf[WS_B1 + e * 64 + l2] = v;
        }
    } else {                        // b2f + b3f + b4f
        {
            int e = t >> 6, l2 = t & 63;
            int oc = 4 * (l2 >> 4) + e, m2 = l2 & 15;
            int oh = m2 >> 2, ow = m2 & 3;
            float v = 0.f;
            if (oc < 12) {
                v = H2b[oc * 16 + oh * 4 + ow];
                for (int icl = 0; icl < 8; ++icl)
                    for (int kh = 0; kh < 5; ++kh)
                        for (int kw = 0; kw < 5; ++kw) {
                            int rr = 2 * oh + kh - 2, cc = 2 * ow + kw - 2;
                            if (rr < 0 || rr >= 8 || cc < 0 || cc >= 8)
                                v -= H2w[((oc * 8 + icl) * 5 + kh) * 5 + kw];
                        }
            }
            wsf[WS_B2 + e * 64 + l2] = v;
        }
        for (int i = t; i < 512; i += 256) {    // b3f: e = nt*4+r
            int e = i >> 6, l2 = i & 63;
            int nt = e >> 2, r = e & 3, ch = l2 >> 4;
            int j = nt * 16 + 4 * ch + r;
            wsf[WS_B3 + e * 64 + l2] = (j < 30) ? H3b[j] : 0.f;
        }
        {                                        // b4f: e = r
            int e = t >> 6, l2 = t & 63, ch = l2 >> 4;
            int j = 4 * ch + e;
            wsf[WS_B4 + e * 64 + l2] = (j < 10) ? outb[j] : 0.f;
        }
    }
}

// ---------------- main kernel: 512 threads, 16 samples, 8 waves ----------------
// LDS (45568 B -> 3 blocks/CU = 24 waves/CU):
//   wave regions @ w*4608 (8x4608=36864): h1c [144 pos][16 ch] half, XOR-
//     swizzled, 16-ch layout (R8-proven); xs0 overlays bytes 0-960.
//   xs1 pool @ 36864 + w*960 (8x960=7680): sample1's padded input; DEAD after
//     conv1 reads -> reused for the wave's two h2 slots (s*384, 384 B each).
//   h3 @ 44544: 16 slots x 64 B.
// Per wave: conv1 for BOTH samples up front (all xs reads before any h1c
// write), then sample passes s=0,1 through the single region. Wave-ordered
// LDS guarantees s1 writes queue behind s0 reads.
// launch_bounds (512,4): cap 128 VGPR ((256,7)-style tighter caps caused the
// R10 spill catastrophe).
#define XS1B 36864
#define H3B3 44544
__global__ __launch_bounds__(512, 4) void modernnet_mfma(
    const float* __restrict__ x, const unsigned int* __restrict__ ws,
    float* __restrict__ out)
{
    __shared__ uint4 lds4[2848];
    char* L = (char*)lds4;
    const int t = threadIdx.x, wave = t >> 6, l = t & 63;
    const int ch = l >> 4, m = l & 15;
    char* base = L + wave * 4608;
    char* x1b  = L + XS1B + wave * 960;
    const int sblk = blockIdx.x * 16;
    const int s0 = sblk + wave * 2;

    const uint4* fr = (const uint4*)ws;
    const float* wsf = (const float*)ws;

    // hoisted global x loads: lanes 0-31 sample0, lanes 32-63 sample1
    const float* xp = x + (size_t)s0 * 256 + l * 8;
    float4 xv0 = *(const float4*)xp;
    float4 xv1 = *(const float4*)(xp + 4);

    // conv1 weight + bias frags
    uint4 c1b0 = fr[0 * 64 + l], c1b1 = fr[1 * 64 + l];
    f32x4 b1f[4];
    #pragma unroll
    for (int tt = 0; tt < 4; ++tt)
        #pragma unroll
        for (int r = 0; r < 4; ++r) b1f[tt][r] = wsf[WS_B1 + (tt * 4 + r) * 64 + l];

    // conv2 per-lane read offsets (16-ch swizzled layout, R8)
    int c2off[13];
    {
        const int mb = 24 * (m >> 2) + 2 * (m & 3);
        const int hb = (ch & 1) << 4;
        const int sel = (ch >> 1) & 1;
        #pragma unroll
        for (int kk = 0; kk < 13; ++kk) {
            const int t0 = 2 * kk;
            const int t1 = (2 * kk + 1 <= 24) ? 2 * kk + 1 : 24;
            const int p0 = (t0 / 5) * 12 + (t0 % 5);
            const int p1 = (t1 / 5) * 12 + (t1 % 5);
            int pos = mb + (sel ? p1 : p0);
            c2off[kk] = ((pos << 5) + hb) ^ ((pos & 12) << 2);
        }
    }

    // zero xs0 (region bytes 0-960) and xs1 (pool bytes 0-960)
    {
        uint4 z; z.x = z.y = z.z = z.w = 0u;
        if (l < 60) {
            ((uint4*)base)[l] = z;
            ((uint4*)x1b)[l] = z;
        }
    }

    // write x interiors -> f16, rows 2-17 cols 2-17 (sample by lane half)
    {
        int sI = l >> 5, idx = l & 31;
        int r = idx >> 1, c = (idx & 1) * 8;
        char* dst = (sI ? x1b : base) + (r + 2) * 48 + (c + 2) * 2;
        ((unsigned int*)dst)[0] = pk(xv0.x, xv0.y);
        ((unsigned int*)dst)[1] = pk(xv0.z, xv0.w);
        ((unsigned int*)dst)[2] = pk(xv1.x, xv1.y);
        ((unsigned int*)dst)[3] = pk(xv1.z, xv1.w);
    }

    // conv1 for BOTH samples: all 10 reads, then 16 MFMAs into acc1[8].
    // rd[s][i] (i<4) = rows 4i+2h+ch (h=m>>3); tile tt uses rd[s][tt] (kh0-3)
    // and rd[s][tt+1] (kh4: only ch=0 lanes carry nonzero c1b1 weights).
    // rd[s][4] read wave-uniform row (ch>0 rows would be OOB junk).
    uint4 rd[2][5];
    #pragma unroll
    for (int s = 0; s < 2; ++s)
        #pragma unroll
        for (int i = 0; i < 5; ++i) {
            const int cho = (i < 4) ? ch * 48 : 0;
            const char* src = (s ? x1b : base)
                + (2 * i + (m >> 3)) * 96 + (m & 7) * 4 + cho;
            const unsigned int* p = (const unsigned int*)src;
            rd[s][i] = make_uint4(p[0], p[1], p[2], p[3]);
        }
    f32x4 acc1[8];
    #pragma unroll
    for (int i = 0; i < 8; ++i) {
        const int s = i >> 2, tt = i & 3;
        f32x4 acc = b1f[tt];
        acc = __builtin_amdgcn_mfma_f32_16x16x32_f16(asH(c1b0), asH(rd[s][tt]), acc, 0, 0, 0);
        acc = __builtin_amdgcn_mfma_f32_16x16x32_f16(asH(c1b1), asH(rd[s][tt + 1]), acc, 0, 0, 0);
        acc1[i] = acc;
    }

    // conv2 weights + bias
    uint4 c2b[13];
    #pragma unroll
    for (int kk = 0; kk < 13; ++kk) c2b[kk] = fr[(2 + kk) * 64 + l];
    f32x4 b2f;
    #pragma unroll
    for (int r = 0; r < 4; ++r) b2f[r] = wsf[WS_B2 + r * 64 + l];

    // -------- sample passes through the single region --------
    #pragma unroll
    for (int s = 0; s < 2; ++s) {
        // conv1 epilogue for sample s: rows=oc in regs -> b64 swizzled writes
        #pragma unroll
        for (int tt = 0; tt < 4; ++tt) {
            const f32x4 acc = acc1[s * 4 + tt];
            const int pos = (2 * tt + (m >> 3) + 2) * 12 + (m & 7) + 2;
            const int off = ((pos << 5) + ch * 8) ^ ((pos & 12) << 2);
            unsigned int w0 = pkr(acc[0], acc[1]);
            unsigned int w1 = pkr(acc[2], acc[3]);
            *(uint2*)(base + off) = make_uint2(w0, w1);
        }

        // zero h1c pad rings (every pass — interior write covers ring bytes)
        {
            uint4 z; z.x = z.y = z.z = z.w = 0u;
            #pragma unroll
            for (int k2 = 0; k2 < 3; ++k2) {
                int idx = l + k2 * 64;          // 0..159
                if (idx < 160) {
                    int pi = idx >> 1, half = idx & 1;
                    int pos;
                    if (pi < 24) pos = pi;
                    else if (pi < 48) pos = pi + 96;
                    else {
                        int q = pi - 48;
                        int c = q & 3; c = (c < 2) ? c : c + 8;
                        pos = (2 + (q >> 2)) * 12 + c;
                    }
                    int off = ((pos << 5) + (half << 4)) ^ ((pos & 12) << 2);
                    *(uint4*)(base + off) = z;
                }
            }
        }

        // conv2: 13 b128 reads + 13 MFMA; h2 slot lives in the xs1 pool
        {
            f32x4 a = b2f;
            #pragma unroll
            for (int kk = 0; kk < 13; ++kk) {
                uint4 r0 = *(const uint4*)(base + c2off[kk]);
                a = __builtin_amdgcn_mfma_f32_16x16x32_f16(asH(c2b[kk]), asH(r0), a, 0, 0, 0);
            }
            if (ch < 3) {
                const int slot = wave * 2 + s;
                const int off = m * 24 + ch * 8;
                unsigned int w0 = pkr(a[0], a[1]);
                unsigned int w1 = pkr(a[2], a[3]);
                *(uint2*)(x1b + s * 384 + (off ^ ((slot & 7) << 4))) = make_uint2(w0, w1);
            }
        }

        // next pass overwrites the region: re-zero xs0 + rewrite interior
        if (s == 0) {
            uint4 z; z.x = z.y = z.z = z.w = 0u;
            (void)z;   // region's xs bytes already hold h1c; s1 uses acc1 only
        }
    }

    // prefetch fc1 frags (waves 0,1; nt = wave)
    uint4 afc[6];
    if (wave < 2) {
        #pragma unroll
        for (int kk = 0; kk < 6; ++kk) afc[kk] = fr[(15 + wave * 6 + kk) * 64 + l];
    }

    __syncthreads();

    // fc1: rows = fc cols (regs), cols = 16 samples (slot = m, pool read)
    if (wave < 2) {
        const int nt = wave;
        f32x4 acc;
        #pragma unroll
        for (int r = 0; r < 4; ++r) acc[r] = wsf[WS_B3 + (nt * 4 + r) * 64 + l];
        #pragma unroll
        for (int kk = 0; kk < 6; ++kk) {
            uint4 bb = *(const uint4*)(L + XS1B + (m >> 1) * 960 + (m & 1) * 384 +
                                       ((kk * 64 + ch * 16) ^ ((m & 7) << 4)));
            acc = __builtin_amdgcn_mfma_f32_16x16x32_f16(asH(afc[kk]), asH(bb), acc, 0, 0, 0);
        }
        // h3[sample m][j] — j>=30 slots hold relu(0)=0 (zero weights+bias)
        unsigned int w0 = pkr(acc[0], acc[1]);
        unsigned int w1 = pkr(acc[2], acc[3]);
        *(uint2*)(L + H3B3 + m * 64 + ((nt * 32 + ch * 8) ^ ((m & 3) << 4))) =
            make_uint2(w0, w1);
    }

    __syncthreads();

    // fc2: wave 0 only, 1 MFMA for all 16 samples
    if (wave == 0) {
        uint4 aw = fr[27 * 64 + l];
        uint4 bb = *(const uint4*)(L + H3B3 + m * 64 +
                                   ((ch * 16) ^ ((m & 3) << 4)));
        f32x4 acc;
        #pragma unroll
        for (int r = 0; r < 4; ++r) acc[r] = wsf[WS_B4 + r * 64 + l];
        acc = __builtin_amdgcn_mfma_f32_16x16x32_f16(asH(aw), asH(bb), acc, 0, 0, 0);
        {
            float* op = out + (size_t)(sblk + m) * 10 + 4 * ch;
            if (ch < 2) {
                *(float2*)op       = make_float2(acc[0], acc[1]);
                *(float2*)(op + 2) = make_float2(acc[2], acc[3]);
            } else if (ch == 2) {
                *(float2*)op       = make_float2(acc[0], acc[1]);
            }
        }
    }
}

extern "C" void kernel_launch(void* const* d_in, const int* in_sizes, int n_in,
                              void* d_out, int out_size, void* d_ws, size_t ws_size,
                              hipStream_t stream) {
    const float* x    = (const float*)d_in[0];
    const float* H1w  = (const float*)d_in[1];
    const float* H1b  = (const float*)d_in[2];
    const float* H2w  = (const float*)d_in[3];
    const float* H2b  = (const float*)d_in[4];
    const float* H3w  = (const float*)d_in[5];
    const float* H3b  = (const float*)d_in[6];
    const float* outw = (const float*)d_in[7];
    const float* outb = (const float*)d_in[8];
    float* outp = (float*)d_out;
    unsigned int* ws = (unsigned int*)d_ws;

    build_tables<<<30, 256, 0, stream>>>(H1w, H1b, H2w, H2b, H3w, H3b, outw, outb, ws);

    const int B = in_sizes[0] / 256;          // 131072
    const int blocks = B / 16;                // 8192
    modernnet_mfma<<<blocks, 512, 0, stream>>>(x, ws, outp);
}